// Round 3
// baseline (265.054 us; speedup 1.0000x reference)
//
#include <hip/hip_runtime.h>
#include <hip/hip_cooperative_groups.h>

namespace cg = cooperative_groups;

#define BB 2
#define NN 256
#define MM 512
#define INF_ 256
#define OUTF 128
#define NEG_INF -1.0e12f

// One cooperative kernel, 512 blocks x 256 threads, 4 phases with grid syncs.
__global__ __launch_bounds__(256, 2) void k_fused(
        const float* __restrict__ X, const float* __restrict__ A,
        const float* __restrict__ W, const float* __restrict__ avec,
        float* __restrict__ H, float* __restrict__ h0,
        float* __restrict__ h1, float* __restrict__ cH,
        float* __restrict__ emA0, float* __restrict__ emA1,
        float* __restrict__ att, float* __restrict__ out) {
    cg::grid_group grid = cg::this_grid();
    const int blk = blockIdx.x;
    const int t = threadIdx.x;
    const int lane = t & 63, wv = t >> 6;

    // ---------------- P1: H = X@W ; h0 = H.a0, h1 = H.a1, cH = leaky(h0+h1)
    // one (b,n) row per block; f = t&127, k-half = t>>7 (split-K 2-way)
    {
        const int bn = blk;                 // 0..511
        const int f = t & 127, kh = t >> 7;
        __shared__ float xs[INF_];
        xs[t] = X[bn * INF_ + t];
        __syncthreads();
        float acc = 0.f;
        const float* Wp = W + kh * 128 * OUTF + f;
        const float* xp = xs + kh * 128;
#pragma unroll 8
        for (int k = 0; k < 128; ++k) acc += xp[k] * Wp[k * OUTF];
        __shared__ float accs[256];
        accs[t] = acc;
        __syncthreads();
        float a2 = 0.f, p0 = 0.f, p1 = 0.f;
        if (t < 128) {
            a2 = accs[t] + accs[t + 128];
            H[bn * OUTF + t] = a2;
            p0 = a2 * avec[t];
            p1 = a2 * avec[OUTF + t];
        }
#pragma unroll
        for (int off = 32; off >= 1; off >>= 1) {
            p0 += __shfl_down(p0, off);
            p1 += __shfl_down(p1, off);
        }
        __shared__ float r0[4], r1[4];
        if (lane == 0) { r0[wv] = p0; r1[wv] = p1; }
        __syncthreads();
        if (t == 0) {
            float s0 = r0[0] + r0[1] + r0[2] + r0[3];
            float s1 = r1[0] + r1[1] + r1[2] + r1[3];
            h0[bn] = s0;
            h1[bn] = s1;
            float hA = s0 + s1;
            cH[bn] = hA > 0.f ? hA : 0.01f * hA;   // leaky_relu 0.01
        }
    }
    __threadfence();
    grid.sync();

    // ---------------- P2 (blocks 0..31): emA0/emA1 = (A^T h)/deg
    if (blk < 32) {
        const int b = blk >> 4, mq = blk & 15;
        const int m_l = t & 31, n_l = t >> 5;
        __shared__ float sh0[NN], sh1[NN];
        sh0[t] = h0[b * NN + t];
        sh1[t] = h1[b * NN + t];
        __syncthreads();
        const float* Ap = A + (size_t)b * NN * MM + mq * 32 + m_l;
        float d = 0.f, s0 = 0.f, s1 = 0.f;
#pragma unroll 8
        for (int i = 0; i < 32; ++i) {
            int n = n_l * 32 + i;
            float av = Ap[n * MM];          // coalesced across m_l
            d += av;
            s0 += av * sh0[n];
            s1 += av * sh1[n];
        }
        __shared__ float sd[256], ss0[256], ss1[256];
        sd[t] = d; ss0[t] = s0; ss1[t] = s1;
        __syncthreads();
        if (t < 32) {
            float D = 0.f, S0 = 0.f, S1 = 0.f;
#pragma unroll
            for (int j = 0; j < 8; ++j) {
                D  += sd[j * 32 + t];
                S0 += ss0[j * 32 + t];
                S1 += ss1[j * 32 + t];
            }
            if (D == 0.f) D = 1.f;
            emA0[b * MM + mq * 32 + t] = S0 / D;
            emA1[b * MM + mq * 32 + t] = S1 / D;
        }
    }
    __threadfence();
    grid.sync();

    // ---------------- P3: masked softmax row -> att; one row per block,
    // each thread owns m = t and m = t+256. Note ev(m) == ev(m+256) for n>=128.
    {
        const int bn = blk;
        const int b = bn >> 8, n = bn & 255;
        float av0 = A[(size_t)bn * MM + t];
        float av1 = A[(size_t)bn * MM + t + 256];
        float ev0, ev1;
        if (n < 128) {
            ev0 = cH[b * NN + 2 * n];       // m <  256 -> s=0
            ev1 = cH[b * NN + 2 * n + 1];   // m >= 256 -> s=1
        } else {
            float v = emA0[b * MM + 2 * t] + emA1[b * MM + 2 * t + 1];
            v = v > 0.f ? v : 0.01f * v;
            ev0 = v; ev1 = v;               // same for m and m+256
        }
        float q0 = av0 > 0.f ? ev0 : NEG_INF;
        float q1 = av1 > 0.f ? ev1 : NEG_INF;
        float mx = fmaxf(q0, q1);
#pragma unroll
        for (int off = 32; off >= 1; off >>= 1) mx = fmaxf(mx, __shfl_xor(mx, off));
        __shared__ float wmx[4];
        if (lane == 0) wmx[wv] = mx;
        __syncthreads();
        float bmx = fmaxf(fmaxf(wmx[0], wmx[1]), fmaxf(wmx[2], wmx[3]));
        float ex0 = expf(q0 - bmx), ex1 = expf(q1 - bmx);
        float s = ex0 + ex1;
#pragma unroll
        for (int off = 32; off >= 1; off >>= 1) s += __shfl_xor(s, off);
        __shared__ float wsm[4];
        if (lane == 0) wsm[wv] = s;
        __syncthreads();
        float inv = 1.f / (wsm[0] + wsm[1] + wsm[2] + wsm[3]);
        att[(size_t)bn * MM + t]       = ex0 * inv;
        att[(size_t)bn * MM + t + 256] = ex1 * inv;
    }
    __threadfence();
    grid.sync();

    // ---------------- P4: out[b,m,f] = sum_n att[b,n,m] * H[b,n,f]
    // 2 m per block; att cols staged in LDS; n split 8-way, float4 over f.
    {
        const int b = blk >> 8, mg = blk & 255;
        const int m0 = 2 * mg, m1 = 2 * mg + 1;
        __shared__ float sA0[NN], sA1[NN];
        sA0[t] = att[((size_t)b * NN + t) * MM + m0];
        sA1[t] = att[((size_t)b * NN + t) * MM + m1];
        __syncthreads();
        const int fg = t & 31, nh = t >> 5;
        const float4* H4 = (const float4*)H + (size_t)b * NN * 32;
        float4 acc0 = {0.f, 0.f, 0.f, 0.f}, acc1 = {0.f, 0.f, 0.f, 0.f};
#pragma unroll 8
        for (int i = 0; i < 32; ++i) {
            int n = nh * 32 + i;
            float4 hv = H4[n * 32 + fg];    // coalesced 16B/lane
            float a0 = sA0[n], a1 = sA1[n]; // LDS broadcast
            acc0.x += a0 * hv.x; acc0.y += a0 * hv.y;
            acc0.z += a0 * hv.z; acc0.w += a0 * hv.w;
            acc1.x += a1 * hv.x; acc1.y += a1 * hv.y;
            acc1.z += a1 * hv.z; acc1.w += a1 * hv.w;
        }
        __shared__ float4 sredA[8][32], sredB[8][32];
        sredA[nh][fg] = acc0;
        sredB[nh][fg] = acc1;
        __syncthreads();
        if (t < 64) {
            int which = t >> 5, fgi = t & 31;
            float4 s = {0.f, 0.f, 0.f, 0.f};
            if (which == 0) {
#pragma unroll
                for (int j = 0; j < 8; ++j) {
                    float4 v = sredA[j][fgi];
                    s.x += v.x; s.y += v.y; s.z += v.z; s.w += v.w;
                }
                ((float4*)out)[((size_t)b * MM + m0) * 32 + fgi] = s;
            } else {
#pragma unroll
                for (int j = 0; j < 8; ++j) {
                    float4 v = sredB[j][fgi];
                    s.x += v.x; s.y += v.y; s.z += v.z; s.w += v.w;
                }
                ((float4*)out)[((size_t)b * MM + m1) * 32 + fgi] = s;
            }
        }
    }
}

extern "C" void kernel_launch(void* const* d_in, const int* in_sizes, int n_in,
                              void* d_out, int out_size, void* d_ws, size_t ws_size,
                              hipStream_t stream) {
    const float* X = (const float*)d_in[0];
    const float* A = (const float*)d_in[1];
    const float* W = (const float*)d_in[2];
    const float* a = (const float*)d_in[3];
    float* out = (float*)d_out;
    float* ws = (float*)d_ws;

    float* H    = ws;            // B*N*OUTF = 65536
    float* h0   = ws + 65536;    // 512
    float* h1   = ws + 66048;    // 512
    float* cH   = ws + 66560;    // 512
    float* emA0 = ws + 67072;    // B*M = 1024
    float* emA1 = ws + 68096;    // B*M = 1024
    float* att  = ws + 69120;    // B*N*M = 262144

    void* args[] = {
        (void*)&X, (void*)&A, (void*)&W, (void*)&a,
        (void*)&H, (void*)&h0, (void*)&h1, (void*)&cH,
        (void*)&emA0, (void*)&emA1, (void*)&att, (void*)&out
    };
    hipLaunchCooperativeKernel((const void*)k_fused, dim3(BB * NN), dim3(256),
                               args, 0, stream);
}

// Round 4
// 26.093 us; speedup vs baseline: 10.1582x; 10.1582x over previous
//
#include <hip/hip_runtime.h>

#define BB 2
#define NN 256
#define MM 512
#define INF_ 256
#define OUTF 128

// K1: H = X@W, plus h0 = H.a0, h1 = H.a1, cH = leaky(h0+h1)
// one block per (b,n) row, 256 threads: f = t&127, k-half = t>>7 (split-K)
__global__ __launch_bounds__(256) void k_gemm(const float* __restrict__ X,
                                              const float* __restrict__ W,
                                              const float* __restrict__ avec,
                                              float* __restrict__ H,
                                              float* __restrict__ h0,
                                              float* __restrict__ h1,
                                              float* __restrict__ cH) {
    int bn = blockIdx.x;      // b*N + n
    int t = threadIdx.x;
    int f = t & 127, kh = t >> 7;
    __shared__ float xs[INF_];
    xs[t] = X[bn * INF_ + t];
    __syncthreads();
    float acc = 0.f;
    const float* Wp = W + kh * 128 * OUTF + f;
    const float* xp = xs + kh * 128;
#pragma unroll 8
    for (int k = 0; k < 128; ++k) acc += xp[k] * Wp[k * OUTF];
    __shared__ float accs[256];
    accs[t] = acc;
    __syncthreads();
    float a2 = 0.f, p0 = 0.f, p1 = 0.f;
    if (t < 128) {
        a2 = accs[t] + accs[t + 128];
        H[bn * OUTF + t] = a2;
        p0 = a2 * avec[t];
        p1 = a2 * avec[OUTF + t];
    }
#pragma unroll
    for (int off = 32; off >= 1; off >>= 1) {
        p0 += __shfl_down(p0, off);
        p1 += __shfl_down(p1, off);
    }
    __shared__ float r0[4], r1[4];
    int wv = t >> 6, ln = t & 63;
    if (ln == 0) { r0[wv] = p0; r1[wv] = p1; }
    __syncthreads();
    if (t == 0) {
        float s0 = r0[0] + r0[1] + r0[2] + r0[3];
        float s1 = r1[0] + r1[1] + r1[2] + r1[3];
        h0[bn] = s0;
        h1[bn] = s1;
        float hA = s0 + s1;
        cH[bn] = hA > 0.f ? hA : 0.01f * hA;   // leaky_relu 0.01
    }
}

// K2: em0[b,m] = (sum_n A*h0)/deg ; em1 likewise (deg 0 -> 1)
// 32 blocks: b = blk>>4, mq = blk&15. 256 thr: m_l = t&31, n_l = t>>5.
__global__ __launch_bounds__(256) void k_em(const float* __restrict__ A,
                                            const float* __restrict__ h0,
                                            const float* __restrict__ h1,
                                            float* __restrict__ em0,
                                            float* __restrict__ em1) {
    int blk = blockIdx.x;
    int b = blk >> 4, mq = blk & 15;
    int t = threadIdx.x;
    int m_l = t & 31, n_l = t >> 5;
    __shared__ float sh0[NN], sh1[NN];
    sh0[t] = h0[b * NN + t];
    sh1[t] = h1[b * NN + t];
    __syncthreads();
    const float* Ap = A + (size_t)b * NN * MM + mq * 32 + m_l;
    float d = 0.f, s0 = 0.f, s1 = 0.f;
#pragma unroll 8
    for (int i = 0; i < 32; ++i) {
        int n = n_l * 32 + i;
        float av = Ap[n * MM];          // coalesced across m_l
        d += av;
        s0 += av * sh0[n];
        s1 += av * sh1[n];
    }
    __shared__ float sd[256], ss0[256], ss1[256];
    sd[t] = d; ss0[t] = s0; ss1[t] = s1;
    __syncthreads();
    if (t < 32) {
        float D = 0.f, S0 = 0.f, S1 = 0.f;
#pragma unroll
        for (int j = 0; j < 8; ++j) {
            D  += sd[j * 32 + t];
            S0 += ss0[j * 32 + t];
            S1 += ss1[j * 32 + t];
        }
        if (D == 0.f) D = 1.f;
        em0[b * MM + mq * 32 + t] = S0 / D;
        em1[b * MM + mq * 32 + t] = S1 / D;
    }
}

// K3: per-row softmax stats (replaces materialized att).
// 128 blocks x 256 thr, 4 rows/block (one per wave).
// n<128:  rs0 = exp(cH0-mx)/sum, rs1 = exp(cH1-mx)/sum  (halves of m)
// n>=128: rs0 = exp(-mx)/sum over active eLow[m], rs1 unused
__global__ __launch_bounds__(256) void k_stats(const float* __restrict__ A,
                                               const float* __restrict__ cH,
                                               const float* __restrict__ em0,
                                               const float* __restrict__ em1,
                                               float* __restrict__ rs0,
                                               float* __restrict__ rs1) {
    int blk = blockIdx.x;
    int t = threadIdx.x;
    int wv = t >> 6, lane = t & 63;
    int bn = blk * 4 + wv;
    int b = bn >> 8, n = bn & 255;
    bool low = ((blk * 4) & 255) < 128;       // uniform per block
    __shared__ float sem0[MM], sem1[MM];
    if (!low) {
        sem0[t] = em0[b * MM + t];
        sem0[t + 256] = em0[b * MM + t + 256];
        sem1[t] = em1[b * MM + t];
        sem1[t + 256] = em1[b * MM + t + 256];
    }
    __syncthreads();
    const float* Ar = A + (size_t)bn * MM;
    if (low) {
        float c0 = 0.f, c1 = 0.f;
#pragma unroll
        for (int i = 0; i < 8; ++i) {
            float av = Ar[lane + 64 * i];
            if (i < 4) c0 += av; else c1 += av;
        }
#pragma unroll
        for (int off = 32; off >= 1; off >>= 1) {
            c0 += __shfl_xor(c0, off);
            c1 += __shfl_xor(c1, off);
        }
        if (lane == 0) {
            float ch0 = cH[b * NN + 2 * n];
            float ch1 = cH[b * NN + 2 * n + 1];
            float mx = fmaxf(c0 > 0.f ? ch0 : -INFINITY,
                             c1 > 0.f ? ch1 : -INFINITY);
            float e0 = c0 > 0.f ? expf(ch0 - mx) : 0.f;
            float e1 = c1 > 0.f ? expf(ch1 - mx) : 0.f;
            float inv = 1.f / (c0 * e0 + c1 * e1);
            rs0[bn] = e0 * inv;
            rs1[bn] = e1 * inv;
        }
    } else {
        float av[8], eL[8];
#pragma unroll
        for (int i = 0; i < 8; ++i) {
            int m = lane + 64 * i;
            av[i] = Ar[m];
            float v = sem0[(2 * m) & (MM - 1)] + sem1[(2 * m + 1) & (MM - 1)];
            eL[i] = v > 0.f ? v : 0.01f * v;
        }
        float mx = -INFINITY;
#pragma unroll
        for (int i = 0; i < 8; ++i) if (av[i] > 0.f) mx = fmaxf(mx, eL[i]);
#pragma unroll
        for (int off = 32; off >= 1; off >>= 1)
            mx = fmaxf(mx, __shfl_xor(mx, off));
        float s = 0.f;
#pragma unroll
        for (int i = 0; i < 8; ++i)
            if (av[i] > 0.f) s += expf(eL[i] - mx);
#pragma unroll
        for (int off = 32; off >= 1; off >>= 1) s += __shfl_xor(s, off);
        if (lane == 0) {
            rs0[bn] = expf(-mx) / s;
            rs1[bn] = 0.f;
        }
    }
}

// K4: out[b,m,f] = sum_n att(b,n,m) * H[b,n,f], att reconstructed inline.
// 512 blocks x 512 thr: b = blk>>8, m-pair mp = blk&255;
// thread = (nh = t>>8, m_l = (t>>7)&1, f = t&127); n split 2-way.
__global__ __launch_bounds__(512) void k_out(const float* __restrict__ A,
                                             const float* __restrict__ H,
                                             const float* __restrict__ em0,
                                             const float* __restrict__ em1,
                                             const float* __restrict__ rs0,
                                             const float* __restrict__ rs1,
                                             float* __restrict__ out) {
    int blk = blockIdx.x;
    int b = blk >> 8, mp = blk & 255;
    int t = threadIdx.x;
    int nh = t >> 8, f = t & 127;
    int m = mp * 2 + ((t >> 7) & 1);
    __shared__ float srs0[NN], srs1[NN];
    if (t < 256) srs0[t] = rs0[b * NN + t];
    else         srs1[t - 256] = rs1[b * NN + (t - 256)];
    float v0 = em0[b * MM + ((2 * m) & (MM - 1))];
    float v1 = em1[b * MM + ((2 * m + 1) & (MM - 1))];
    float vv = v0 + v1;
    vv = vv > 0.f ? vv : 0.01f * vv;
    float eExp = expf(vv);                  // exp(eLow[m])
    __syncthreads();
    const float* Ap = A + (size_t)b * NN * MM + m;
    const float* Hp = H + (size_t)b * NN * OUTF + f;
    float acc = 0.f;
    if (nh == 0) {
        const float* s = (mp < 128) ? srs0 : srs1;   // m<256 ? w0 : w1
#pragma unroll 8
        for (int n = 0; n < 128; ++n) {
            float av = Ap[n * MM];          // wave-broadcast load
            acc = fmaf(av * s[n], Hp[n * OUTF], acc);
        }
    } else {
#pragma unroll 8
        for (int j = 0; j < 128; ++j) {
            int n = 128 + j;
            float av = Ap[n * MM];
            acc = fmaf(av * (eExp * srs0[n]), Hp[n * OUTF], acc);
        }
    }
    __shared__ float sacc[512];
    sacc[t] = acc;
    __syncthreads();
    if (t < 256) {
        float r = sacc[t] + sacc[t + 256];
        int mo = mp * 2 + ((t >> 7) & 1);
        out[((size_t)b * MM + mo) * OUTF + f] = r;
    }
}

extern "C" void kernel_launch(void* const* d_in, const int* in_sizes, int n_in,
                              void* d_out, int out_size, void* d_ws, size_t ws_size,
                              hipStream_t stream) {
    const float* X = (const float*)d_in[0];
    const float* A = (const float*)d_in[1];
    const float* W = (const float*)d_in[2];
    const float* a = (const float*)d_in[3];
    float* out = (float*)d_out;
    float* ws = (float*)d_ws;

    float* H   = ws;            // B*N*OUTF = 65536
    float* h0  = ws + 65536;    // 512
    float* h1  = ws + 66048;    // 512
    float* cH  = ws + 66560;    // 512
    float* em0 = ws + 67072;    // B*M = 1024
    float* em1 = ws + 68096;    // B*M = 1024
    float* rs0 = ws + 69120;    // B*N = 512
    float* rs1 = ws + 69632;    // B*N = 512

    k_gemm<<<BB * NN, 256, 0, stream>>>(X, W, a, H, h0, h1, cH);
    k_em<<<32, 256, 0, stream>>>(A, h0, h1, em0, em1);
    k_stats<<<128, 256, 0, stream>>>(A, cH, em0, em1, rs0, rs1);
    k_out<<<512, 512, 0, stream>>>(A, H, em0, em1, rs0, rs1, out);
}